// Round 7
// baseline (1437.947 us; speedup 1.0000x reference)
//
#include <hip/hip_runtime.h>
#include <hip/hip_bf16.h>
#include <math.h>

// PropagationBlock round 7 (= round 4 kernel, resubmitted after three GPU
// acquisition timeouts): transposed edge MFMA (C^T free via operand swap)
// + packed bf16 atomics (global_atomic_pk_add_bf16) -> atomic bytes 750->375MB.
// Round-3 finding: edge kernel is atomic-RMW-bound at ~1.26 TB/s.

typedef __attribute__((ext_vector_type(8))) short bf16x8;  // 8 bf16 (4 VGPRs)
typedef __attribute__((ext_vector_type(4))) float f32x4;

__device__ __forceinline__ float silu_f(float x) { return x / (1.0f + __expf(-x)); }

__device__ __forceinline__ unsigned cvt_pk_bf16(float lo, float hi) {
  unsigned r;
  asm("v_cvt_pk_bf16_f32 %0, %1, %2" : "=v"(r) : "v"(lo), "v"(hi));
  return r;
}
__device__ __forceinline__ float bf_lo(unsigned w) { return __uint_as_float(w << 16); }
__device__ __forceinline__ float bf_hi(unsigned w) { return __uint_as_float(w & 0xFFFF0000u); }

// packed 2xbf16 atomic add (memory-side, no return). addr 4B-aligned.
__device__ __forceinline__ void atomic_pk_add_bf16(unsigned short* p, unsigned d) {
  asm volatile("global_atomic_pk_add_bf16 %0, %1, off" :: "v"(p), "v"(d) : "memory");
}

// ---------------------------------------------------------------- prep mats
// P = C1+C2, Q = C2-C1 ; C1=(n2e_M1@Mvv)/2, C2=(n2e_M2@Mvv)/4, Mvv=(vv1+vv2)/2
// R = (e2n_M1+e2n_M2)/2, S = (e2n_M2-e2n_M1)/2
__global__ __launch_bounds__(1024) void prep_mats_kernel(
    const float* __restrict__ n2e_M1, const float* __restrict__ n2e_M2,
    const float* __restrict__ vv_M1, const float* __restrict__ vv_M2,
    const float* __restrict__ e2n_M1, const float* __restrict__ e2n_M2,
    float* __restrict__ PQRS) {
  __shared__ float Mvv[32][32];
  int j = threadIdx.x & 31, i = threadIdx.x >> 5;
  Mvv[i][j] = 0.5f * (vv_M1[i * 32 + j] + vv_M2[i * 32 + j]);
  __syncthreads();
  float c1 = 0.f, c2 = 0.f;
#pragma unroll
  for (int k = 0; k < 32; k++) {
    c1 += n2e_M1[i * 32 + k] * Mvv[k][j];
    c2 += n2e_M2[i * 32 + k] * Mvv[k][j];
  }
  c1 *= 0.5f;
  c2 *= 0.25f;
  PQRS[0 * 1024 + i * 32 + j] = c1 + c2;                                          // P [k][col]
  PQRS[1 * 1024 + i * 32 + j] = c2 - c1;                                          // Q [k][col]
  PQRS[2 * 1024 + i * 32 + j] = 0.5f * (e2n_M1[i * 32 + j] + e2n_M2[i * 32 + j]); // R
  PQRS[3 * 1024 + i * 32 + j] = 0.5f * (e2n_M2[i * 32 + j] - e2n_M1[i * 32 + j]); // S
}

// ---------------------------------------------------------------- premix
// xn2b = bf16( cos(a)*xn + sin(a)*(((xn@M)*attr)@M^T) )
__global__ __launch_bounds__(256) void node_premix_kernel(
    const float* __restrict__ xn, const float* __restrict__ xn_attr,
    const float* __restrict__ ms_M, const float* __restrict__ ms_w,
    unsigned short* __restrict__ xn2b, int n_nodes) {
  __shared__ float M[32][33];
  for (int idx = threadIdx.x; idx < 1024; idx += blockDim.x)
    M[idx >> 5][idx & 31] = ms_M[idx];
  __syncthreads();

  int lane = threadIdx.x & 31;
  int grp = blockIdx.x * (blockDim.x >> 5) + (threadIdx.x >> 5);
  if (grp >= n_nodes) return;

  float angle = 0.1f * ms_w[0];
  float ca = cosf(angle), sa = sinf(angle);

  const float* xp = xn + (size_t)grp * 96;
  float x0 = xp[lane], x1 = xp[32 + lane], x2 = xp[64 + lane];

  float t0 = 0.f, t1 = 0.f, t2 = 0.f;
#pragma unroll
  for (int v = 0; v < 32; v++) {
    float m = M[v][lane];
    t0 += __shfl(x0, v, 32) * m;
    t1 += __shfl(x1, v, 32) * m;
    t2 += __shfl(x2, v, 32) * m;
  }
  float attr = xn_attr[(size_t)grp * 32 + lane];
  t0 *= attr; t1 *= attr; t2 *= attr;

  float y0 = 0.f, y1 = 0.f, y2 = 0.f;
#pragma unroll
  for (int s = 0; s < 32; s++) {
    float m = M[lane][s];
    y0 += __shfl(t0, s, 32) * m;
    y1 += __shfl(t1, s, 32) * m;
    y2 += __shfl(t2, s, 32) * m;
  }

  unsigned short* op = xn2b + (size_t)grp * 96;
  op[lane]      = (unsigned short)cvt_pk_bf16(ca * x0 + sa * y0, 0.f);
  op[32 + lane] = (unsigned short)cvt_pk_bf16(ca * x1 + sa * y1, 0.f);
  op[64 + lane] = (unsigned short)cvt_pk_bf16(ca * x2 + sa * y2, 0.f);
}

// ---------------------------------------------------------------- edge MFMA
// Transposed: D[v x e] = P^T@(w1*xs)^T + Q^T@(w1*xd)^T (operand-swapped mfma;
// A/B fragments share the same lane mapping so the swap is free).
// Lane holds its OWN edge (e = lane&15) and 4 contiguous v per tile ->
// epilogue has no shuffles and packs pairs for bf16 packed atomics.
__global__ __launch_bounds__(256) void edge_mfma_kernel(
    const unsigned short* __restrict__ xn2b, const float* __restrict__ xe_attr,
    const int* __restrict__ xe_src, const int* __restrict__ xe_dst,
    const float* __restrict__ fc1_w, const float* __restrict__ fc1_b,
    const float* __restrict__ fc2_w, const float* __restrict__ fc2_b,
    const float* __restrict__ Pg, const float* __restrict__ Qg,
    unsigned short* __restrict__ acc1, unsigned short* __restrict__ acc2,
    int n_edges) {
  int lane = threadIdx.x & 63;
  int row16 = lane & 15;   // edge index within tile
  int koct = lane >> 4;    // k-octet 0..3

  // A-operand fragments = P^T/Q^T tiles: lane holds P[k=koct*8+j][16t+row16].
  union { unsigned u[4]; bf16x8 v; } PA0, PA1, QA0, QA1;
#pragma unroll
  for (int w = 0; w < 4; w++) {
    int k0 = koct * 8 + 2 * w;
    PA0.u[w] = cvt_pk_bf16(Pg[k0 * 32 + row16],      Pg[(k0 + 1) * 32 + row16]);
    PA1.u[w] = cvt_pk_bf16(Pg[k0 * 32 + row16 + 16], Pg[(k0 + 1) * 32 + row16 + 16]);
    QA0.u[w] = cvt_pk_bf16(Qg[k0 * 32 + row16],      Qg[(k0 + 1) * 32 + row16]);
    QA1.u[w] = cvt_pk_bf16(Qg[k0 * 32 + row16 + 16], Qg[(k0 + 1) * 32 + row16 + 16]);
  }

  float f1wj[8], f1bj[8];   // k = koct*8 + j
#pragma unroll
  for (int j = 0; j < 8; j++) {
    f1wj[j] = fc1_w[koct * 8 + j];
    f1bj[j] = fc1_b[koct * 8 + j];
  }
  float f2wv[8], f2bv[8];   // v = tt*16 + koct*4 + rr  (j = tt*4+rr)
#pragma unroll
  for (int j = 0; j < 4; j++) {
    f2wv[j]     = fc2_w[koct * 4 + j];      f2bv[j]     = fc2_b[koct * 4 + j];
    f2wv[4 + j] = fc2_w[16 + koct * 4 + j]; f2bv[4 + j] = fc2_b[16 + koct * 4 + j];
  }

  int wid = blockIdx.x * (blockDim.x >> 6) + (threadIdx.x >> 6);
  int wstride = gridDim.x * (blockDim.x >> 6);
  int ntiles = (n_edges + 15) >> 4;

  for (int t = wid; t < ntiles; t += wstride) {
    int ebase = t << 4;
    int e = ebase + row16;
    int ec = e < n_edges ? e : n_edges - 1;
    int sn = xe_src[ec], dn = xe_dst[ec];
    float ea = xe_attr[ec];

    float w1[8];
#pragma unroll
    for (int j = 0; j < 8; j++) w1[j] = silu_f(ea * f1wj[j] + f1bj[j]);

    f32x4 ct[3][2];
#pragma unroll
    for (int d = 0; d < 3; d++) {
      ct[d][0] = f32x4{0.f, 0.f, 0.f, 0.f};
      ct[d][1] = f32x4{0.f, 0.f, 0.f, 0.f};
    }

#pragma unroll
    for (int d = 0; d < 3; d++) {
      uint4 aw = *(const uint4*)(xn2b + (size_t)sn * 96 + d * 32 + koct * 8);
      uint4 bw = *(const uint4*)(xn2b + (size_t)dn * 96 + d * 32 + koct * 8);
      unsigned awa[4] = {aw.x, aw.y, aw.z, aw.w};
      unsigned bwa[4] = {bw.x, bw.y, bw.z, bw.w};
      union { unsigned u[4]; bf16x8 v; } AF, BF;
#pragma unroll
      for (int w = 0; w < 4; w++) {
        AF.u[w] = cvt_pk_bf16(bf_lo(awa[w]) * w1[2 * w], bf_hi(awa[w]) * w1[2 * w + 1]);
        BF.u[w] = cvt_pk_bf16(bf_lo(bwa[w]) * w1[2 * w], bf_hi(bwa[w]) * w1[2 * w + 1]);
      }
      // operand-swapped: D = (P^T tile)@(X^T) = C^T
      ct[d][0] = __builtin_amdgcn_mfma_f32_16x16x32_bf16(PA0.v, AF.v, ct[d][0], 0, 0, 0);
      ct[d][0] = __builtin_amdgcn_mfma_f32_16x16x32_bf16(QA0.v, BF.v, ct[d][0], 0, 0, 0);
      ct[d][1] = __builtin_amdgcn_mfma_f32_16x16x32_bf16(PA1.v, AF.v, ct[d][1], 0, 0, 0);
      ct[d][1] = __builtin_amdgcn_mfma_f32_16x16x32_bf16(QA1.v, BF.v, ct[d][1], 0, 0, 0);
    }

    // Epilogue: lane owns edge e = ebase+row16, v = tt*16 + koct*4 + rr.
    if (e < n_edges) {
      float w2v[8];
#pragma unroll
      for (int j = 0; j < 8; j++) w2v[j] = silu_f(ea * f2wv[j] + f2bv[j]);

      size_t offD = (size_t)dn * 96;
      size_t offS = (size_t)sn * 96;
#pragma unroll
      for (int d = 0; d < 3; d++) {
#pragma unroll
        for (int tt = 0; tt < 2; tt++) {
          int vo = d * 32 + tt * 16 + koct * 4;
          unsigned u0 = cvt_pk_bf16(ct[d][tt][0] * w2v[tt * 4 + 0],
                                    ct[d][tt][1] * w2v[tt * 4 + 1]);
          unsigned u1 = cvt_pk_bf16(ct[d][tt][2] * w2v[tt * 4 + 2],
                                    ct[d][tt][3] * w2v[tt * 4 + 3]);
          atomic_pk_add_bf16(acc1 + offD + vo, u0);
          atomic_pk_add_bf16(acc1 + offD + vo + 2, u1);
          atomic_pk_add_bf16(acc2 + offS + vo, u0);
          atomic_pk_add_bf16(acc2 + offS + vo + 2, u1);
        }
      }
    }
  }
}

// ---------------------------------------------------------------- node post
// out = acc1@R + acc2@S, then x * tanh(||x||_dim). accs are bf16.
__global__ __launch_bounds__(256) void node_post_kernel(
    const __hip_bfloat16* __restrict__ acc1, const __hip_bfloat16* __restrict__ acc2,
    const float* __restrict__ Rg, const float* __restrict__ Sg,
    float* __restrict__ out, int n_nodes) {
  __shared__ float R[32][32], S[32][32];
  for (int idx = threadIdx.x; idx < 1024; idx += blockDim.x) {
    R[idx >> 5][idx & 31] = Rg[idx];
    S[idx >> 5][idx & 31] = Sg[idx];
  }
  __syncthreads();
  int lane = threadIdx.x & 31;
  int grp = blockIdx.x * (blockDim.x >> 5) + (threadIdx.x >> 5);
  if (grp >= n_nodes) return;
  const __hip_bfloat16* a = acc1 + (size_t)grp * 96;
  const __hip_bfloat16* b = acc2 + (size_t)grp * 96;
  float a0 = __bfloat162float(a[lane]);
  float a1 = __bfloat162float(a[32 + lane]);
  float a2 = __bfloat162float(a[64 + lane]);
  float b0 = __bfloat162float(b[lane]);
  float b1 = __bfloat162float(b[32 + lane]);
  float b2 = __bfloat162float(b[64 + lane]);
  float y0 = 0.f, y1 = 0.f, y2 = 0.f;
#pragma unroll
  for (int v = 0; v < 32; v++) {
    float r = R[v][lane], s = S[v][lane];
    y0 += __shfl(a0, v, 32) * r + __shfl(b0, v, 32) * s;
    y1 += __shfl(a1, v, 32) * r + __shfl(b1, v, 32) * s;
    y2 += __shfl(a2, v, 32) * r + __shfl(b2, v, 32) * s;
  }
  float nrm = sqrtf(y0 * y0 + y1 * y1 + y2 * y2);
  float t = tanhf(nrm);
  float* op = out + (size_t)grp * 96;
  op[lane]      = y0 * t;
  op[32 + lane] = y1 * t;
  op[64 + lane] = y2 * t;
}

// ---------------------------------------------------------------- launch
extern "C" void kernel_launch(void* const* d_in, const int* in_sizes, int n_in,
                              void* d_out, int out_size, void* d_ws, size_t ws_size,
                              hipStream_t stream) {
  const float* xn      = (const float*)d_in[0];
  const float* xn_attr = (const float*)d_in[1];
  const float* xe_attr = (const float*)d_in[2];
  const int*   xe_src  = (const int*)d_in[3];
  const int*   xe_dst  = (const int*)d_in[4];
  const float* ms_M    = (const float*)d_in[5];
  const float* ms_w    = (const float*)d_in[6];
  const float* fc1_w   = (const float*)d_in[7];
  const float* fc1_b   = (const float*)d_in[8];
  const float* fc2_w   = (const float*)d_in[9];
  const float* fc2_b   = (const float*)d_in[10];
  const float* n2e_M1  = (const float*)d_in[11];
  const float* n2e_M2  = (const float*)d_in[12];
  const float* vv_M1   = (const float*)d_in[13];
  const float* vv_M2   = (const float*)d_in[14];
  const float* e2n_M1  = (const float*)d_in[15];
  const float* e2n_M2  = (const float*)d_in[16];

  int n_nodes = in_sizes[0] / 96;
  int n_edges = in_sizes[2];

  char* base = (char*)d_ws;
  float* PQRS = (float*)base;                                    // 16 KB
  unsigned short* xn2b = (unsigned short*)(base + 16384);        // 9.6 MB bf16 nodes
  unsigned short* acc1 = (unsigned short*)(base + 16384 + (size_t)n_nodes * 96 * 2);
  unsigned short* acc2 = acc1 + (size_t)n_nodes * 96;

  prep_mats_kernel<<<1, 1024, 0, stream>>>(n2e_M1, n2e_M2, vv_M1, vv_M2,
                                           e2n_M1, e2n_M2, PQRS);

  int nblk = (n_nodes + 7) / 8;
  node_premix_kernel<<<nblk, 256, 0, stream>>>(xn, xn_attr, ms_M, ms_w, xn2b, n_nodes);

  hipMemsetAsync(acc1, 0, (size_t)n_nodes * 96 * 2 * sizeof(unsigned short), stream);

  edge_mfma_kernel<<<4096, 256, 0, stream>>>(xn2b, xe_attr, xe_src, xe_dst,
                                             fc1_w, fc1_b, fc2_w, fc2_b,
                                             PQRS, PQRS + 1024, acc1, acc2, n_edges);

  node_post_kernel<<<nblk, 256, 0, stream>>>((__hip_bfloat16*)acc1, (__hip_bfloat16*)acc2,
                                             PQRS + 2048, PQRS + 3072,
                                             (float*)d_out, n_nodes);
}